// Round 1
// baseline (58.787 us; speedup 1.0000x reference)
//
#include <hip/hip_runtime.h>

// Rate-1/2, K=7 non-recursive conv encoder.
// G1 = 1011011 -> taps at delays {0,2,3,5,6}
// G2 = 1111001 -> taps at delays {0,1,2,3,6}
// out0[t] = m[t]^m[t-2]^m[t-3]^m[t-5]^m[t-6]
// out1[t] = m[t]^m[t-1]^m[t-2]^m[t-3]^m[t-6]
// cw[b, 2t] = out0[t], cw[b, 2t+1] = out1[t]

#define K_BITS 4096
#define CHUNK  32
#define CHUNKS_PER_ROW (K_BITS / CHUNK)   // 128

__global__ __launch_bounds__(256) void conv_encode_kernel(
        const float* __restrict__ in, float* __restrict__ out) {
    const int tid   = blockIdx.x * 256 + threadIdx.x;
    const int row   = tid >> 7;           // 128 chunks per row
    const int chunk = tid & 127;
    const int base  = chunk << 5;         // *32

    const float* p = in + (size_t)row * K_BITS + base;

    // Pack 32 main bits into w[6..37]; w[0..5] = 6 bits of history (msg[base-6..base-1]).
    unsigned long long w = 0ull;
#pragma unroll
    for (int k = 0; k < 8; ++k) {
        const float4 v = *reinterpret_cast<const float4*>(p + 4 * k);
        unsigned long long nib =
              (unsigned long long)(v.x != 0.0f)
            | ((unsigned long long)(v.y != 0.0f) << 1)
            | ((unsigned long long)(v.z != 0.0f) << 2)
            | ((unsigned long long)(v.w != 0.0f) << 3);
        w |= nib << (6 + 4 * k);
    }
    if (chunk != 0) {
        // history floats msg[base-8 .. base-1]; we need base-6 .. base-1
        const float4 h0 = *reinterpret_cast<const float4*>(p - 8);
        const float4 h1 = *reinterpret_cast<const float4*>(p - 4);
        unsigned long long hb =
              (unsigned long long)(h0.z != 0.0f)          // msg[base-6] -> bit 0
            | ((unsigned long long)(h0.w != 0.0f) << 1)
            | ((unsigned long long)(h1.x != 0.0f) << 2)
            | ((unsigned long long)(h1.y != 0.0f) << 3)
            | ((unsigned long long)(h1.z != 0.0f) << 4)
            | ((unsigned long long)(h1.w != 0.0f) << 5);
        w |= hb;
    }

    // Bit-sliced parity streams: output bit i (time base+i) lives at bit i.
    const unsigned long long y0 = (w >> 6) ^ (w >> 4) ^ (w >> 3) ^ (w >> 1) ^ w;
    const unsigned long long y1 = (w >> 6) ^ (w >> 5) ^ (w >> 4) ^ (w >> 3) ^ w;

    float* q = out + (size_t)row * (K_BITS * 2) + (size_t)base * 2;
#pragma unroll
    for (int i = 0; i < 32; i += 2) {
        float4 o;
        o.x = (float)((y0 >> i) & 1ull);
        o.y = (float)((y1 >> i) & 1ull);
        o.z = (float)((y0 >> (i + 1)) & 1ull);
        o.w = (float)((y1 >> (i + 1)) & 1ull);
        *reinterpret_cast<float4*>(q + 2 * i) = o;
    }
}

extern "C" void kernel_launch(void* const* d_in, const int* in_sizes, int n_in,
                              void* d_out, int out_size, void* d_ws, size_t ws_size,
                              hipStream_t stream) {
    const float* in = (const float*)d_in[0];   // [B, 4096] of 0.0/1.0
    float* out = (float*)d_out;                // [B, 8192]

    const int B = in_sizes[0] / K_BITS;        // 2048
    const int total_threads = B * CHUNKS_PER_ROW;
    const int blocks = (total_threads + 255) / 256;

    conv_encode_kernel<<<blocks, 256, 0, stream>>>(in, out);
}

// Round 2
// 23.588 us; speedup vs baseline: 2.4923x; 2.4923x over previous
//
#include <hip/hip_runtime.h>

// Rate-1/2, K=7 non-recursive conv encoder, B x 4096 -> B x 8192.
// out0[t] = m[t]^m[t-2]^m[t-3]^m[t-5]^m[t-6]   (G1 = 1011011)
// out1[t] = m[t]^m[t-1]^m[t-2]^m[t-3]^m[t-6]   (G2 = 1111001)
// cw[b, 2t] = out0[t], cw[b, 2t+1] = out1[t]
//
// R2 design: one thread = one float4 of OUTPUT (2 time steps). Wave stores are
// 64 lanes x 16B fully contiguous (1KB dense per instruction) -> no partial-line
// write amplification (R1 had 256B lane stride -> 3.3x WRITE_SIZE).

#define K_BITS 4096
#define THREADS_PER_ROW (K_BITS / 2)   // 2048: each thread emits 2 time steps

__device__ __forceinline__ unsigned bit_of(float v) {
    // v is exactly 0.0f or 1.0f -> exponent-bit0 (0x3F800000) is the value.
    return (__float_as_uint(v) >> 23) & 1u;
}

__global__ __launch_bounds__(256) void conv_encode_kernel(
        const float* __restrict__ in, float* __restrict__ out) {
    const int tid = blockIdx.x * 256 + threadIdx.x;
    const int row = tid >> 11;            // /2048
    const int idx = tid & 2047;
    const int t0  = idx << 1;             // first time step this thread emits

    const float* p = in + (size_t)row * K_BITS;

    // w bit k = m[t0-6+k], k=0..7 (history < 0 is zero-state)
    unsigned w = 0;
    if (idx >= 3) {
        const float4 a = *reinterpret_cast<const float4*>(p + t0 - 6);
        const float4 b = *reinterpret_cast<const float4*>(p + t0 - 2);
        w =  bit_of(a.x)
          | (bit_of(a.y) << 1)
          | (bit_of(a.z) << 2)
          | (bit_of(a.w) << 3)
          | (bit_of(b.x) << 4)
          | (bit_of(b.y) << 5)
          | (bit_of(b.z) << 6)
          | (bit_of(b.w) << 7);
    } else {
#pragma unroll
        for (int k = 0; k < 8; ++k) {
            const int t = t0 - 6 + k;
            if (t >= 0) w |= bit_of(p[t]) << k;
        }
    }

    // out0[t0+i] = bit i of y0; out1[t0+i] = bit i of y1
    const unsigned y0 = (w >> 6) ^ (w >> 4) ^ (w >> 3) ^ (w >> 1) ^ w;
    const unsigned y1 = (w >> 6) ^ (w >> 5) ^ (w >> 4) ^ (w >> 3) ^ w;

    float4 o;
    o.x = (float)( y0       & 1u);
    o.y = (float)( y1       & 1u);
    o.z = (float)((y0 >> 1) & 1u);
    o.w = (float)((y1 >> 1) & 1u);
    *reinterpret_cast<float4*>(out + (size_t)tid * 4) = o;
}

extern "C" void kernel_launch(void* const* d_in, const int* in_sizes, int n_in,
                              void* d_out, int out_size, void* d_ws, size_t ws_size,
                              hipStream_t stream) {
    const float* in = (const float*)d_in[0];   // [B, 4096] of 0.0/1.0
    float* out = (float*)d_out;                // [B, 8192]

    const int B = in_sizes[0] / K_BITS;        // 2048
    const int total_threads = B * THREADS_PER_ROW;
    const int blocks = (total_threads + 255) / 256;

    conv_encode_kernel<<<blocks, 256, 0, stream>>>(in, out);
}